// Round 1
// baseline (1603.258 us; speedup 1.0000x reference)
//
#include <hip/hip_runtime.h>
#include <hip/hip_bf16.h>
#include <math.h>

#define DIMD 256
#define NTOK 8192
#define NCODE 8192

#define BM 64          // rows per WG (pass1: tokens, pass2: codes)
#define BK 256         // cols per tile (pass1: codes, pass2: tokens)
#define DC 32          // depth chunk
#define KSPLIT 2
#define KHALF (NCODE / KSPLIT)   // 4096
#define KT_PER (KHALF / BK)      // 16
#define NHALF (NTOK / KSPLIT)    // 4096
#define NT_PER (NHALF / BK)      // 16

__device__ __forceinline__ float4 ldg4(const float* p) {
    return *reinterpret_cast<const float4*>(p);
}

// ---------------------------------------------------------------- prep_z
// z: (32, 256, 16, 16) -> z_norm [8192][256], n = (b*16+h)*16+w, L2-normalized rows
__global__ __launch_bounds__(256) void prep_z(const float* __restrict__ z, float* __restrict__ zn)
{
    int bh = blockIdx.x;           // b*16 + h, 0..511
    int c  = threadIdx.x;          // 0..255
    const float* src = z + (size_t)(bh >> 4) * 65536 + (size_t)c * 256 + (size_t)(bh & 15) * 16;
    float v[16];
    float4 t0 = ldg4(src + 0), t1 = ldg4(src + 4), t2 = ldg4(src + 8), t3 = ldg4(src + 12);
    v[0]=t0.x; v[1]=t0.y; v[2]=t0.z; v[3]=t0.w;
    v[4]=t1.x; v[5]=t1.y; v[6]=t1.z; v[7]=t1.w;
    v[8]=t2.x; v[9]=t2.y; v[10]=t2.z; v[11]=t2.w;
    v[12]=t3.x; v[13]=t3.y; v[14]=t3.z; v[15]=t3.w;

    float sq[16];
    #pragma unroll
    for (int w = 0; w < 16; ++w) sq[w] = v[w] * v[w];
    #pragma unroll
    for (int o = 32; o > 0; o >>= 1) {
        #pragma unroll
        for (int w = 0; w < 16; ++w) sq[w] += __shfl_xor(sq[w], o, 64);
    }
    __shared__ float part[4][16];
    __shared__ float inv[16];
    int wave = c >> 6, lane = c & 63;
    if (lane == 0) {
        #pragma unroll
        for (int w = 0; w < 16; ++w) part[wave][w] = sq[w];
    }
    __syncthreads();
    if (c < 16) {
        float s = part[0][c] + part[1][c] + part[2][c] + part[3][c];
        inv[c] = 1.0f / sqrtf(s + 1e-12f);
    }
    __syncthreads();
    #pragma unroll
    for (int w = 0; w < 16; ++w) {
        zn[(size_t)(bh * 16 + w) * DIMD + c] = v[w] * inv[w];
    }
}

// ---------------------------------------------------------------- prep_e
// embedding [8192][256] -> e_norm, e_sq[k] = sum(e_norm^2) (post-rounding, like ref)
__global__ __launch_bounds__(256) void prep_e(const float* __restrict__ e, float* __restrict__ en,
                                              float* __restrict__ esq, float* __restrict__ scal)
{
    if (blockIdx.x == 0 && threadIdx.x < 2) scal[threadIdx.x] = 0.0f;
    int row  = blockIdx.x * 4 + (threadIdx.x >> 6);
    int lane = threadIdx.x & 63;
    const float* src = e + (size_t)row * DIMD + lane * 4;
    float4 v = ldg4(src);
    float ss = v.x*v.x + v.y*v.y + v.z*v.z + v.w*v.w;
    #pragma unroll
    for (int o = 32; o > 0; o >>= 1) ss += __shfl_xor(ss, o, 64);
    float inv = 1.0f / sqrtf(ss + 1e-12f);
    float4 w4;
    w4.x = v.x * inv; w4.y = v.y * inv; w4.z = v.z * inv; w4.w = v.w * inv;
    *reinterpret_cast<float4*>(en + (size_t)row * DIMD + lane * 4) = w4;
    float s2 = w4.x*w4.x + w4.y*w4.y + w4.z*w4.z + w4.w*w4.w;
    #pragma unroll
    for (int o = 32; o > 0; o >>= 1) s2 += __shfl_xor(s2, o, 64);
    if (lane == 0) esq[row] = s2;
}

// ---------------------------------------------------------------- pass1
// For each token row: online softmax over logits l = 200*dot - 100*esq[k]
// (per-row const -100*zsq dropped: softmax/argmax invariant).
// K split in 2 halves; partial (m, s, u=sum e^(l-m)(l-m), argmax idx) written per half.
__global__ __launch_bounds__(256) void pass1(const float* __restrict__ zn, const float* __restrict__ en,
                                             const float* __restrict__ esq,
                                             float* __restrict__ pm, float* __restrict__ ps,
                                             float* __restrict__ pu, int* __restrict__ pbi)
{
    __shared__ float At[DC][BM];    // [d][token]
    __shared__ float Bt[DC][BK];    // [d][code]
    const int tid = threadIdx.x;
    const int tx = tid & 31, ty = tid >> 5;
    const int n0 = (blockIdx.x >> 1) * BM;
    const int half = blockIdx.x & 1;
    const int kbase = half * KHALF;

    float m[8], s[8], u[8];
    int bi[8];
    #pragma unroll
    for (int i = 0; i < 8; ++i) { m[i] = -3.0e38f; s[i] = 0.f; u[i] = 0.f; bi[i] = 0; }

    for (int kt = 0; kt < KT_PER; ++kt) {
        const int k0 = kbase + kt * BK;
        float acc[8][8];
        #pragma unroll
        for (int i = 0; i < 8; ++i)
            #pragma unroll
            for (int j = 0; j < 8; ++j) acc[i][j] = 0.f;

        for (int dc = 0; dc < DIMD; dc += DC) {
            __syncthreads();
            #pragma unroll
            for (int L = tid; L < BM * DC / 4; L += 256) {     // 2 iters
                int r = L >> 3, dq = L & 7;
                float4 vv = ldg4(zn + (size_t)(n0 + r) * DIMD + dc + dq * 4);
                At[dq*4+0][r] = vv.x; At[dq*4+1][r] = vv.y;
                At[dq*4+2][r] = vv.z; At[dq*4+3][r] = vv.w;
            }
            #pragma unroll
            for (int L = tid; L < BK * DC / 4; L += 256) {     // 8 iters
                int rr = L >> 3, dq = L & 7;
                float4 vv = ldg4(en + (size_t)(k0 + rr) * DIMD + dc + dq * 4);
                Bt[dq*4+0][rr] = vv.x; Bt[dq*4+1][rr] = vv.y;
                Bt[dq*4+2][rr] = vv.z; Bt[dq*4+3][rr] = vv.w;
            }
            __syncthreads();
            #pragma unroll
            for (int dk = 0; dk < DC; ++dk) {
                float4 a0 = *(const float4*)&At[dk][ty*8];
                float4 a1 = *(const float4*)&At[dk][ty*8+4];
                float4 b0 = *(const float4*)&Bt[dk][tx*4];
                float4 b1 = *(const float4*)&Bt[dk][128 + tx*4];
                float av[8] = {a0.x,a0.y,a0.z,a0.w,a1.x,a1.y,a1.z,a1.w};
                float bv[8] = {b0.x,b0.y,b0.z,b0.w,b1.x,b1.y,b1.z,b1.w};
                #pragma unroll
                for (int i = 0; i < 8; ++i)
                    #pragma unroll
                    for (int j = 0; j < 8; ++j)
                        acc[i][j] = fmaf(av[i], bv[j], acc[i][j]);
            }
        }
        // fused online softmax / argmax update; cols j map to k = k0 + tx*4 + (j&3) + (j>>2)*128
        float eq[8];
        #pragma unroll
        for (int j = 0; j < 8; ++j) eq[j] = esq[k0 + tx*4 + (j&3) + (j>>2)*128];
        #pragma unroll
        for (int i = 0; i < 8; ++i) {
            float l[8];
            #pragma unroll
            for (int j = 0; j < 8; ++j) l[j] = fmaf(200.f, acc[i][j], -100.f * eq[j]);
            float lv = l[0]; int li = k0 + tx*4;
            #pragma unroll
            for (int j = 1; j < 8; ++j) {
                int ci = k0 + tx*4 + (j&3) + (j>>2)*128;
                if (l[j] > lv) { lv = l[j]; li = ci; }   // ascending ci -> first max kept
            }
            #pragma unroll
            for (int o = 16; o > 0; o >>= 1) {
                float ov = __shfl_xor(lv, o, 32);
                int   oi = __shfl_xor(li, o, 32);
                if (ov > lv || (ov == lv && oi < li)) { lv = ov; li = oi; }
            }
            if (lv > m[i]) bi[i] = li;         // ties keep earlier (smaller k) tile's index
            float mn = fmaxf(m[i], lv);
            float psum = 0.f, usum = 0.f;
            #pragma unroll
            for (int j = 0; j < 8; ++j) {
                float x = l[j] - mn;
                float ee = __expf(x);
                psum += ee; usum += ee * x;
            }
            #pragma unroll
            for (int o = 16; o > 0; o >>= 1) {
                psum += __shfl_xor(psum, o, 32);
                usum += __shfl_xor(usum, o, 32);
            }
            float dm = m[i] - mn;              // finite sentinel, <= 0
            float al = __expf(dm);
            u[i] = al * (u[i] + s[i] * dm) + usum;
            s[i] = al * s[i] + psum;
            m[i] = mn;
        }
    }
    if (tx == 0) {
        #pragma unroll
        for (int i = 0; i < 8; ++i) {
            int n = n0 + ty*8 + i;
            int o = half * NTOK + n;
            pm[o] = m[i]; ps[o] = s[i]; pu[o] = u[i]; pbi[o] = bi[i];
        }
    }
}

// ---------------------------------------------------------------- merge halves
__global__ __launch_bounds__(256) void merge_halves(const float* __restrict__ pm, const float* __restrict__ ps,
                                                    const float* __restrict__ pu, const int* __restrict__ pbi,
                                                    float* __restrict__ mls, int* __restrict__ idx,
                                                    float* __restrict__ samp)
{
    int n = blockIdx.x * 256 + threadIdx.x;
    float m0 = pm[n], m1 = pm[NTOK + n];
    float s0 = ps[n], s1 = ps[NTOK + n];
    float u0 = pu[n], u1 = pu[NTOK + n];
    int b0 = pbi[n], b1 = pbi[NTOK + n];
    float mm = fmaxf(m0, m1);
    float a0 = __expf(m0 - mm), a1 = __expf(m1 - mm);
    float ss = a0 * s0 + a1 * s1;
    float uu = a0 * (u0 + s0 * (m0 - mm)) + a1 * (u1 + s1 * (m1 - mm));
    float lnS = logf(ss);
    mls[n] = mm + lnS;
    idx[n] = (m1 > m0) ? b1 : b0;              // tie -> half 0 (smaller k), matches argmin-first
    float plogp = uu / ss - lnS;               // sum_k p*log p for this row
    __shared__ float red[256];
    red[threadIdx.x] = plogp;
    __syncthreads();
    for (int o = 128; o > 0; o >>= 1) {
        if (threadIdx.x < o) red[threadIdx.x] += red[threadIdx.x + o];
        __syncthreads();
    }
    if (threadIdx.x == 0) atomicAdd(samp, red[0]);
}

// ---------------------------------------------------------------- pass2
// avg_probs: recompute dots with roles swapped (rows=codes). Each WG owns 64 codes
// x one token-half; writes its avgp slice non-atomically (deterministic).
__global__ __launch_bounds__(256) void pass2(const float* __restrict__ en, const float* __restrict__ zn,
                                             const float* __restrict__ esq, const float* __restrict__ mls,
                                             float* __restrict__ avgp)
{
    __shared__ float At[DC][BM];    // [d][code]
    __shared__ float Bt[DC][BK];    // [d][token]
    const int tid = threadIdx.x;
    const int tx = tid & 31, ty = tid >> 5;
    const int k0 = (blockIdx.x >> 1) * BM;
    const int half = blockIdx.x & 1;
    const int nbase = half * NHALF;

    float eq[8];
    #pragma unroll
    for (int i = 0; i < 8; ++i) eq[i] = esq[k0 + ty*8 + i];
    float av[8];
    #pragma unroll
    for (int i = 0; i < 8; ++i) av[i] = 0.f;

    for (int nt = 0; nt < NT_PER; ++nt) {
        const int nn0 = nbase + nt * BK;
        float acc[8][8];
        #pragma unroll
        for (int i = 0; i < 8; ++i)
            #pragma unroll
            for (int j = 0; j < 8; ++j) acc[i][j] = 0.f;

        for (int dc = 0; dc < DIMD; dc += DC) {
            __syncthreads();
            #pragma unroll
            for (int L = tid; L < BM * DC / 4; L += 256) {
                int r = L >> 3, dq = L & 7;
                float4 vv = ldg4(en + (size_t)(k0 + r) * DIMD + dc + dq * 4);
                At[dq*4+0][r] = vv.x; At[dq*4+1][r] = vv.y;
                At[dq*4+2][r] = vv.z; At[dq*4+3][r] = vv.w;
            }
            #pragma unroll
            for (int L = tid; L < BK * DC / 4; L += 256) {
                int rr = L >> 3, dq = L & 7;
                float4 vv = ldg4(zn + (size_t)(nn0 + rr) * DIMD + dc + dq * 4);
                Bt[dq*4+0][rr] = vv.x; Bt[dq*4+1][rr] = vv.y;
                Bt[dq*4+2][rr] = vv.z; Bt[dq*4+3][rr] = vv.w;
            }
            __syncthreads();
            #pragma unroll
            for (int dk = 0; dk < DC; ++dk) {
                float4 a0 = *(const float4*)&At[dk][ty*8];
                float4 a1 = *(const float4*)&At[dk][ty*8+4];
                float4 b0 = *(const float4*)&Bt[dk][tx*4];
                float4 b1 = *(const float4*)&Bt[dk][128 + tx*4];
                float avv[8] = {a0.x,a0.y,a0.z,a0.w,a1.x,a1.y,a1.z,a1.w};
                float bvv[8] = {b0.x,b0.y,b0.z,b0.w,b1.x,b1.y,b1.z,b1.w};
                #pragma unroll
                for (int i = 0; i < 8; ++i)
                    #pragma unroll
                    for (int j = 0; j < 8; ++j)
                        acc[i][j] = fmaf(avv[i], bvv[j], acc[i][j]);
            }
        }
        float mj[8];
        #pragma unroll
        for (int j = 0; j < 8; ++j) mj[j] = mls[nn0 + tx*4 + (j&3) + (j>>2)*128];
        #pragma unroll
        for (int i = 0; i < 8; ++i) {
            #pragma unroll
            for (int j = 0; j < 8; ++j) {
                float l = fmaf(200.f, acc[i][j], -100.f * eq[i]);
                av[i] += __expf(l - mj[j]);
            }
        }
    }
    #pragma unroll
    for (int i = 0; i < 8; ++i) {
        #pragma unroll
        for (int o = 16; o > 0; o >>= 1) av[i] += __shfl_xor(av[i], o, 32);
    }
    if (tx == 0) {
        #pragma unroll
        for (int i = 0; i < 8; ++i) avgp[half * NCODE + k0 + ty*8 + i] = av[i];
    }
}

// ---------------------------------------------------------------- gather z_q + vq sum
__global__ __launch_bounds__(256) void gather_zq(const float* __restrict__ en, const float* __restrict__ zn,
                                                 const int* __restrict__ idx, float* __restrict__ out,
                                                 float* __restrict__ vq)
{
    int bh = blockIdx.x;     // b*16 + h
    int c  = threadIdx.x;
    float buf[16];
    float sum = 0.f;
    #pragma unroll
    for (int w = 0; w < 16; ++w) {
        int n = bh * 16 + w;
        int k = idx[n];
        float q  = en[(size_t)k * DIMD + c];
        float zv = zn[(size_t)n * DIMD + c];
        float dd = q - zv;
        sum += dd * dd;
        buf[w] = q;
    }
    float* dst = out + (size_t)(bh >> 4) * 65536 + (size_t)c * 256 + (size_t)(bh & 15) * 16;
    *(float4*)(dst + 0)  = make_float4(buf[0],  buf[1],  buf[2],  buf[3]);
    *(float4*)(dst + 4)  = make_float4(buf[4],  buf[5],  buf[6],  buf[7]);
    *(float4*)(dst + 8)  = make_float4(buf[8],  buf[9],  buf[10], buf[11]);
    *(float4*)(dst + 12) = make_float4(buf[12], buf[13], buf[14], buf[15]);
    #pragma unroll
    for (int o = 32; o > 0; o >>= 1) sum += __shfl_xor(sum, o, 64);
    __shared__ float red[4];
    if ((c & 63) == 0) red[c >> 6] = sum;
    __syncthreads();
    if (c == 0) atomicAdd(vq, red[0] + red[1] + red[2] + red[3]);
}

// ---------------------------------------------------------------- finalize scalars
__global__ __launch_bounds__(256) void finalize(const float* __restrict__ avgp, const float* __restrict__ scal,
                                                float* __restrict__ out3)
{
    int tid = threadIdx.x;
    float local = 0.f;
    for (int k = tid; k < NCODE; k += 256) {
        float a = (avgp[k] + avgp[NCODE + k]) * (1.0f / 8192.0f);
        local += a * logf(a + 1e-5f);
    }
    __shared__ float red[256];
    red[tid] = local;
    __syncthreads();
    for (int o = 128; o > 0; o >>= 1) {
        if (tid < o) red[tid] += red[tid + o];
        __syncthreads();
    }
    if (tid == 0) {
        float avg_entropy = -red[0];
        float sample_entropy = -(scal[0] * (1.0f / 8192.0f));
        float ent = 0.1f * (sample_entropy - avg_entropy);
        float vql = scal[1] * (1.0f / 2097152.0f);
        out3[0] = vql;
        out3[1] = 0.25f * vql;
        out3[2] = ent;
    }
}

extern "C" void kernel_launch(void* const* d_in, const int* in_sizes, int n_in,
                              void* d_out, int out_size, void* d_ws, size_t ws_size,
                              hipStream_t stream)
{
    const float* z   = (const float*)d_in[0];
    const float* emb = (const float*)d_in[1];
    float* ws = (float*)d_ws;

    float* zn   = ws;                          // 2097152
    float* en   = ws + 2097152;                // 2097152
    float* esq  = ws + 4194304;                // 8192
    float* mls  = esq + 8192;                  // 8192
    int*   idx  = (int*)(mls + 8192);          // 8192
    float* pm   = (float*)(idx + 8192);        // 16384
    float* ps_  = pm + 16384;                  // 16384
    float* pu   = ps_ + 16384;                 // 16384
    int*   pbi  = (int*)(pu + 16384);          // 16384
    float* avgp = (float*)(pbi + 16384);       // 16384
    float* scal = avgp + 16384;                // [0]=samp_plogp_sum, [1]=vq_sum

    float* outq = (float*)d_out;               // z_q: 2097152
    float* out3 = outq + 2097152;              // 3 scalars

    prep_z<<<512, 256, 0, stream>>>(z, zn);
    prep_e<<<2048, 256, 0, stream>>>(emb, en, esq, scal);
    pass1<<<256, 256, 0, stream>>>(zn, en, esq, pm, ps_, pu, pbi);
    merge_halves<<<32, 256, 0, stream>>>(pm, ps_, pu, pbi, mls, idx, scal);
    pass2<<<256, 256, 0, stream>>>(en, zn, esq, mls, avgp);
    gather_zq<<<512, 256, 0, stream>>>(en, zn, idx, outq, scal + 1);
    finalize<<<1, 256, 0, stream>>>(avgp, scal, out3);
}

// Round 3
// 375.901 us; speedup vs baseline: 4.2651x; 4.2651x over previous
//
#include <hip/hip_runtime.h>
#include <math.h>

#define NTOK 8192
#define NCODE 8192
#define DIMD 256

typedef __bf16 bf16x8 __attribute__((ext_vector_type(8)));
typedef float f32x4 __attribute__((ext_vector_type(4)));

__device__ __forceinline__ float4 ldg4(const float* p) {
    return *reinterpret_cast<const float4*>(p);
}
__device__ __forceinline__ unsigned short f2bh(float x) {
    __bf16 h = (__bf16)x;
    return __builtin_bit_cast(unsigned short, h);
}
__device__ __forceinline__ float bh2f(unsigned short u) {
    return (float)__builtin_bit_cast(__bf16, u);
}
__device__ __forceinline__ void gl16(const void* g, void* l) {
    __builtin_amdgcn_global_load_lds(
        (const __attribute__((address_space(1))) unsigned int*)g,
        (__attribute__((address_space(3))) unsigned int*)l, 16, 0, 0);
}

// ---------------------------------------------------------------- prep_z
// z (32,256,16,16) -> normalized rows as bf16 hi/lo [8192][256] + zinv[8192]
__global__ __launch_bounds__(256) void prep_z(const float* __restrict__ z,
    unsigned short* __restrict__ zzh, unsigned short* __restrict__ zzl,
    float* __restrict__ zinvp)
{
    int bh = blockIdx.x;           // b*16 + h
    int c  = threadIdx.x;          // channel
    const float* src = z + (size_t)(bh >> 4) * 65536 + (size_t)c * 256 + (size_t)(bh & 15) * 16;
    float v[16];
    float4 t0 = ldg4(src + 0), t1 = ldg4(src + 4), t2 = ldg4(src + 8), t3 = ldg4(src + 12);
    v[0]=t0.x; v[1]=t0.y; v[2]=t0.z; v[3]=t0.w;
    v[4]=t1.x; v[5]=t1.y; v[6]=t1.z; v[7]=t1.w;
    v[8]=t2.x; v[9]=t2.y; v[10]=t2.z; v[11]=t2.w;
    v[12]=t3.x; v[13]=t3.y; v[14]=t3.z; v[15]=t3.w;

    float sq[16];
#pragma unroll
    for (int w = 0; w < 16; ++w) sq[w] = v[w] * v[w];
#pragma unroll
    for (int o = 32; o > 0; o >>= 1) {
#pragma unroll
        for (int w = 0; w < 16; ++w) sq[w] += __shfl_xor(sq[w], o, 64);
    }
    __shared__ float part[4][16];
    __shared__ float invS[16];
    int wave = c >> 6, lane = c & 63;
    if (lane == 0) {
#pragma unroll
        for (int w = 0; w < 16; ++w) part[wave][w] = sq[w];
    }
    __syncthreads();
    if (c < 16) {
        float s = part[0][c] + part[1][c] + part[2][c] + part[3][c];
        float iv = 1.0f / sqrtf(s + 1e-12f);
        invS[c] = iv;
        zinvp[bh * 16 + c] = iv;
    }
    __syncthreads();
#pragma unroll
    for (int w = 0; w < 16; ++w) {
        float nv = v[w] * invS[w];
        unsigned short h = f2bh(nv);
        float lo = nv - bh2f(h);
        size_t o = (size_t)(bh * 16 + w) * DIMD + c;
        zzh[o] = h;
        zzl[o] = f2bh(lo);
    }
}

// ---------------------------------------------------------------- prep_e
__global__ __launch_bounds__(256) void prep_e(const float* __restrict__ e,
    unsigned short* __restrict__ eeh, unsigned short* __restrict__ eel,
    float* __restrict__ esq, float* __restrict__ einvp,
    float* __restrict__ avgp, float* __restrict__ scal)
{
    if (blockIdx.x == 0 && threadIdx.x < 2) scal[threadIdx.x] = 0.0f;
    if (blockIdx.x < 32) avgp[blockIdx.x * 256 + threadIdx.x] = 0.0f;
    int row  = blockIdx.x * 4 + (threadIdx.x >> 6);
    int lane = threadIdx.x & 63;
    float4 v = ldg4(e + (size_t)row * DIMD + lane * 4);
    float ss = v.x*v.x + v.y*v.y + v.z*v.z + v.w*v.w;
#pragma unroll
    for (int o = 32; o > 0; o >>= 1) ss += __shfl_xor(ss, o, 64);
    float inv = 1.0f / sqrtf(ss + 1e-12f);
    float w4[4] = { v.x*inv, v.y*inv, v.z*inv, v.w*inv };
    unsigned short hs[4], ls[4];
#pragma unroll
    for (int j = 0; j < 4; ++j) {
        hs[j] = f2bh(w4[j]);
        ls[j] = f2bh(w4[j] - bh2f(hs[j]));
    }
    uint2 ph, pl;
    ph.x = (unsigned)hs[0] | ((unsigned)hs[1] << 16);
    ph.y = (unsigned)hs[2] | ((unsigned)hs[3] << 16);
    pl.x = (unsigned)ls[0] | ((unsigned)ls[1] << 16);
    pl.y = (unsigned)ls[2] | ((unsigned)ls[3] << 16);
    *(uint2*)(eeh + (size_t)row * DIMD + lane * 4) = ph;
    *(uint2*)(eel + (size_t)row * DIMD + lane * 4) = pl;
    float s2 = w4[0]*w4[0] + w4[1]*w4[1] + w4[2]*w4[2] + w4[3]*w4[3];
#pragma unroll
    for (int o = 32; o > 0; o >>= 1) s2 += __shfl_xor(s2, o, 64);
    if (lane == 0) { esq[row] = s2; einvp[row] = inv; }
}

// ---------------------------------------------------------------- pass1
// D[code][token] MFMA GEMM (hi/lo bf16, 3 terms), online softmax (m,s,u) +
// top-2 (value,index) per token, fully in-register. 512 thr = 8 waves =
// 4 code-groups x 2 token-groups. WG: 64 tokens (staged once) x 4096 codes
// (one half), streamed 256 codes/iter in K-chunks of 32 (double-buffered).
__global__ __launch_bounds__(512) void pass1(
    const unsigned short* __restrict__ eh, const unsigned short* __restrict__ el,
    const unsigned short* __restrict__ zh, const unsigned short* __restrict__ zl,
    const float* __restrict__ esq,
    float* __restrict__ pm1, int* __restrict__ pi1, int* __restrict__ pi2,
    float* __restrict__ psv, float* __restrict__ puv)
{
    __shared__ __align__(16) unsigned short sOwnH[64][264];   // tokens hi (padded rows)
    __shared__ __align__(16) unsigned short sOwnL[64][264];   // tokens lo
    __shared__ __align__(16) unsigned short sStr[2][2][256][32]; // [buf][hi/lo][code][feat]

    const int tid = threadIdx.x;
    const int lane = tid & 63;
    const int wv = tid >> 6;
    const int cg = wv & 3;
    const int tg = wv >> 2;
    const int tkbase = (int)(blockIdx.x >> 1) * 64;
    const int half = blockIdx.x & 1;
    const int kbase = half * 4096;

    // stage own tokens (once)
    {
        int r = tid >> 3, q = tid & 7;
        const uint4* gh  = (const uint4*)(zh + (size_t)(tkbase + r) * DIMD + q * 32);
        const uint4* gl_ = (const uint4*)(zl + (size_t)(tkbase + r) * DIMD + q * 32);
        uint4* dh = (uint4*)&sOwnH[r][q * 32];
        uint4* dl = (uint4*)&sOwnL[r][q * 32];
#pragma unroll
        for (int i = 0; i < 4; ++i) { dh[i] = gh[i]; dl[i] = gl_[i]; }
    }

    const int g = lane >> 4;
    const int rl = lane & 15;
    const int rot = (g + (lane & 3)) & 3;                 // 16B-slot rotation (read side)
    const int strOff = (cg * 64 + rl) * 64 + rot * 16;    // streamed frag base (bytes)
    const int ownOff = (tg * 32 + rl) * 528 + g * 16;     // own frag base (bytes)
    const int srow = lane >> 2;
    const int sg = ((lane & 3) - srow) & 3;               // pre-swizzled source slot
    const int Rb = wv * 32;

    const f32x4 zero4 = {0.f, 0.f, 0.f, 0.f};
    f32x4 acc[4][2];
#pragma unroll
    for (int a = 0; a < 4; ++a)
#pragma unroll
        for (int b = 0; b < 2; ++b) acc[a][b] = zero4;

    float m1[2], m2[2], sS[2], uU[2];
    int i1[2], i2[2];
#pragma unroll
    for (int t = 0; t < 2; ++t) { m1[t] = -3.0e38f; m2[t] = -3.0e38f; sS[t] = 0.f; uU[t] = 0.f; i1[t] = 0; i2[t] = 0; }

    // stage chunk 0
    {
#pragma unroll
        for (int i = 0; i < 2; ++i) {
            size_t go = (size_t)(kbase + Rb + i * 16 + srow) * DIMD + sg * 8;
            gl16(eh + go, &sStr[0][0][Rb + i * 16][0]);
            gl16(el + go, &sStr[0][1][Rb + i * 16][0]);
        }
    }
    __syncthreads();

    for (int c = 0; c < 128; ++c) {
        if (c < 127) {
            int cn = c + 1;
            int b = cn & 1, dc = cn & 7, it = cn >> 3;
            int ktb = kbase + it * 256;
#pragma unroll
            for (int i = 0; i < 2; ++i) {
                size_t go = (size_t)(ktb + Rb + i * 16 + srow) * DIMD + dc * 32 + sg * 8;
                gl16(eh + go, &sStr[b][0][Rb + i * 16][0]);
                gl16(el + go, &sStr[b][1][Rb + i * 16][0]);
            }
        }
        {
            const int b = c & 1, dc = c & 7;
            const char* sb = (const char*)sStr + b * 32768;
            bf16x8 ef[4][2];
#pragma unroll
            for (int cf = 0; cf < 4; ++cf) {
                ef[cf][0] = *(const bf16x8*)(sb + strOff + cf * 1024);
                ef[cf][1] = *(const bf16x8*)(sb + 16384 + strOff + cf * 1024);
            }
            const char* zbH = (const char*)sOwnH;
            const char* zbL = (const char*)sOwnL;
            bf16x8 zf[2][2];
#pragma unroll
            for (int tf = 0; tf < 2; ++tf) {
                zf[tf][0] = *(const bf16x8*)(zbH + ownOff + tf * 8448 + dc * 64);
                zf[tf][1] = *(const bf16x8*)(zbL + ownOff + tf * 8448 + dc * 64);
            }
#pragma unroll
            for (int cf = 0; cf < 4; ++cf)
#pragma unroll
                for (int tf = 0; tf < 2; ++tf) {
                    acc[cf][tf] = __builtin_amdgcn_mfma_f32_16x16x32_bf16(ef[cf][0], zf[tf][0], acc[cf][tf], 0, 0, 0);
                    acc[cf][tf] = __builtin_amdgcn_mfma_f32_16x16x32_bf16(ef[cf][0], zf[tf][1], acc[cf][tf], 0, 0, 0);
                    acc[cf][tf] = __builtin_amdgcn_mfma_f32_16x16x32_bf16(ef[cf][1], zf[tf][0], acc[cf][tf], 0, 0, 0);
                }
        }
        if ((c & 7) == 7) {
            const int it = c >> 3;
            const int codeB = kbase + it * 256 + cg * 64 + g * 4;
#pragma unroll
            for (int tf = 0; tf < 2; ++tf) {
                float t1 = -3.0e38f, t2 = -3.0e38f;
                int ti1 = 0, ti2 = 0;
#pragma unroll
                for (int cf = 0; cf < 4; ++cf) {
                    f32x4 q = *(const f32x4*)(esq + codeB + cf * 16);
                    f32x4 a = acc[cf][tf];
#pragma unroll
                    for (int r = 0; r < 4; ++r) {
                        float x = fmaf(200.f, a[r], -100.f * q[r]);
                        acc[cf][tf][r] = x;                   // keep logits for exp
                        int cid = codeB + cf * 16 + r;
                        bool c1 = x > t1;
                        bool c2 = x > t2;
                        float nt2 = c1 ? t1 : (c2 ? x : t2);
                        int nti2 = c1 ? ti1 : (c2 ? cid : ti2);
                        t1 = c1 ? x : t1;
                        ti1 = c1 ? cid : ti1;
                        t2 = nt2; ti2 = nti2;
                    }
                }
#pragma unroll
                for (int off = 16; off <= 32; off <<= 1) {
                    float o1 = __shfl_xor(t1, off, 64); int oi1 = __shfl_xor(ti1, off, 64);
                    float o2 = __shfl_xor(t2, off, 64); int oi2 = __shfl_xor(ti2, off, 64);
                    bool ow = (o1 > t1) || (o1 == t1 && oi1 < ti1);
                    float w2 = ow ? o2 : t2; int wi2 = ow ? oi2 : ti2;
                    float lo1 = ow ? t1 : o1; int loi1 = ow ? ti1 : oi1;
                    bool s2 = (w2 > lo1) || (w2 == lo1 && wi2 < loi1);
                    t1 = ow ? o1 : t1; ti1 = ow ? oi1 : ti1;
                    t2 = s2 ? w2 : lo1; ti2 = s2 ? wi2 : loi1;
                }
                float mOld = m1[tf];
                {
                    bool bw = (t1 > m1[tf]) || (t1 == m1[tf] && ti1 < i1[tf]);
                    float w2 = bw ? t2 : m2[tf]; int wi2 = bw ? ti2 : i2[tf];
                    float lo1 = bw ? m1[tf] : t1; int loi1 = bw ? i1[tf] : ti1;
                    bool s2 = (w2 > lo1) || (w2 == lo1 && wi2 < loi1);
                    m1[tf] = bw ? t1 : m1[tf]; i1[tf] = bw ? ti1 : i1[tf];
                    m2[tf] = s2 ? w2 : lo1; i2[tf] = s2 ? wi2 : loi1;
                }
                float mn = m1[tf];
                float ps = 0.f, pu = 0.f;
#pragma unroll
                for (int cf = 0; cf < 4; ++cf)
#pragma unroll
                    for (int r = 0; r < 4; ++r) {
                        float x = acc[cf][tf][r] - mn;
                        float e2 = __expf(x);
                        ps += e2;
                        pu = fmaf(e2, x, pu);
                    }
                ps += __shfl_xor(ps, 16, 64); ps += __shfl_xor(ps, 32, 64);
                pu += __shfl_xor(pu, 16, 64); pu += __shfl_xor(pu, 32, 64);
                float dm = mOld - mn;
                float al = __expf(dm);
                uU[tf] = al * (uU[tf] + sS[tf] * dm) + pu;
                sS[tf] = al * sS[tf] + ps;
#pragma unroll
                for (int cf = 0; cf < 4; ++cf) acc[cf][tf] = zero4;
            }
        }
        __syncthreads();
    }

    // cross-wave (code-group) merge
    float* sRed = (float*)sStr;
    if (lane < 16) {
#pragma unroll
        for (int tf = 0; tf < 2; ++tf) {
            int t = tg * 32 + tf * 16 + lane;
            float* p = sRed + (cg * 64 + t) * 6;
            p[0] = m1[tf]; p[1] = __int_as_float(i1[tf]); p[2] = m2[tf];
            p[3] = __int_as_float(i2[tf]); p[4] = sS[tf]; p[5] = uU[tf];
        }
    }
    __syncthreads();
    if (tid < 64) {
        const float* p0 = sRed + tid * 6;
        float am1 = p0[0], am2 = p0[2], as_ = p0[4], au = p0[5];
        int ai1 = __float_as_int(p0[1]), ai2 = __float_as_int(p0[3]);
#pragma unroll
        for (int cgi = 1; cgi < 4; ++cgi) {
            const float* pb = sRed + (cgi * 64 + tid) * 6;
            float bm1 = pb[0], bm2 = pb[2], bs = pb[4], bu = pb[5];
            int bi1 = __float_as_int(pb[1]), bi2 = __float_as_int(pb[3]);
            float M = fmaxf(am1, bm1);
            float da = am1 - M, db = bm1 - M;
            float ea = __expf(da), eb = __expf(db);
            float ns = ea * as_ + eb * bs;
            float nu = ea * (au + as_ * da) + eb * (bu + bs * db);
            bool bw = (bm1 > am1) || (bm1 == am1 && bi1 < ai1);
            float w2 = bw ? bm2 : am2; int wi2 = bw ? bi2 : ai2;
            float lo1 = bw ? am1 : bm1; int loi1 = bw ? ai1 : bi1;
            bool s2 = (w2 > lo1) || (w2 == lo1 && wi2 < loi1);
            am1 = bw ? bm1 : am1; ai1 = bw ? bi1 : ai1;
            am2 = s2 ? w2 : lo1; ai2 = s2 ? wi2 : loi1;
            as_ = ns; au = nu;
        }
        int o = half * NTOK + tkbase + tid;
        pm1[o] = am1; pi1[o] = ai1; pi2[o] = ai2; psv[o] = as_; puv[o] = au;
    }
}

// ---------------------------------------------------------------- merge_halves
__global__ __launch_bounds__(256) void merge_halves(
    const float* __restrict__ pm1, const float* __restrict__ psv, const float* __restrict__ puv,
    float* __restrict__ mls, float* __restrict__ samp)
{
    int n = blockIdx.x * 256 + threadIdx.x;
    float m0 = pm1[n], m1_ = pm1[NTOK + n];
    float s0 = psv[n], s1 = psv[NTOK + n];
    float u0 = puv[n], u1 = puv[NTOK + n];
    float M = fmaxf(m0, m1_);
    float d0 = m0 - M, d1 = m1_ - M;
    float e0 = __expf(d0), e1 = __expf(d1);
    float ss = e0 * s0 + e1 * s1;
    float uu = e0 * (u0 + s0 * d0) + e1 * (u1 + s1 * d1);
    float lnS = logf(ss);
    mls[n] = M + lnS;
    float plogp = uu / ss - lnS;
    __shared__ float red[256];
    red[threadIdx.x] = plogp;
    __syncthreads();
    for (int o = 128; o > 0; o >>= 1) {
        if (threadIdx.x < o) red[threadIdx.x] += red[threadIdx.x + o];
        __syncthreads();
    }
    if (threadIdx.x == 0) atomicAdd(samp, red[0]);
}

// ---------------------------------------------------------------- fixup
// exact f32 argmin over the 4 bf16 top-2 candidates (2 per half), ref tie rules
__global__ __launch_bounds__(512) void fixup(const float* __restrict__ z, const float* __restrict__ zinvp,
    const float* __restrict__ emb, const float* __restrict__ einvp, const float* __restrict__ esq,
    const int* __restrict__ pi1, const int* __restrict__ pi2, int* __restrict__ idx)
{
    int wv = threadIdx.x >> 6, lane = threadIdx.x & 63;
    int n = blockIdx.x * 8 + wv;
    int cand[4] = { pi1[n], pi2[n], pi1[NTOK + n], pi2[NTOK + n] };
    int b = n >> 8, hw = n & 255;
    float zi = zinvp[n];
    float dd[4] = {0.f, 0.f, 0.f, 0.f};
    const float* zp = z + (size_t)b * 65536 + hw;
    for (int d = lane; d < 256; d += 64) {
        float zv = zp[(size_t)d * 256] * zi;
#pragma unroll
        for (int k = 0; k < 4; ++k) dd[k] = fmaf(zv, emb[(size_t)cand[k] * 256 + d], dd[k]);
    }
#pragma unroll
    for (int off = 1; off < 64; off <<= 1) {
#pragma unroll
        for (int k = 0; k < 4; ++k) dd[k] += __shfl_xor(dd[k], off, 64);
    }
    if (lane == 0) {
        float bD = 3.0e38f; int bi = 0x7fffffff;
#pragma unroll
        for (int k = 0; k < 4; ++k) {
            float D = esq[cand[k]] - 2.f * dd[k] * einvp[cand[k]];
            bool win = (D < bD) || (D == bD && cand[k] < bi);
            bD = win ? D : bD; bi = win ? cand[k] : bi;
        }
        idx[n] = bi;
    }
}

// ---------------------------------------------------------------- pass2
// avg_probs: D[token][code], WG owns 64 codes (staged once), streams tokens.
__global__ __launch_bounds__(512) void pass2(
    const unsigned short* __restrict__ eh, const unsigned short* __restrict__ el,
    const unsigned short* __restrict__ zh, const unsigned short* __restrict__ zl,
    const float* __restrict__ esq, const float* __restrict__ mls,
    float* __restrict__ avgp)
{
    __shared__ __align__(16) unsigned short sOwnH[64][264];   // codes
    __shared__ __align__(16) unsigned short sOwnL[64][264];
    __shared__ __align__(16) unsigned short sStr[2][2][256][32]; // tokens

    const int tid = threadIdx.x;
    const int lane = tid & 63;
    const int wv = tid >> 6;
    const int tg4 = wv & 3;      // token group (64 each within 256-tile)
    const int cg2 = wv >> 2;     // code half (32 each)
    const int cbase = (int)(blockIdx.x >> 1) * 64;
    const int half = blockIdx.x & 1;
    const int nbase = half * 4096;

    {
        int r = tid >> 3, q = tid & 7;
        const uint4* gh  = (const uint4*)(eh + (size_t)(cbase + r) * DIMD + q * 32);
        const uint4* gl_ = (const uint4*)(el + (size_t)(cbase + r) * DIMD + q * 32);
        uint4* dh = (uint4*)&sOwnH[r][q * 32];
        uint4* dl = (uint4*)&sOwnL[r][q * 32];
#pragma unroll
        for (int i = 0; i < 4; ++i) { dh[i] = gh[i]; dl[i] = gl_[i]; }
    }

    const int g = lane >> 4;
    const int rl = lane & 15;
    const int rot = (g + (lane & 3)) & 3;
    const int strOff = (tg4 * 64 + rl) * 64 + rot * 16;
    const int ownOff = (cg2 * 32 + rl) * 528 + g * 16;
    const int srow = lane >> 2;
    const int sg = ((lane & 3) - srow) & 3;
    const int Rb = wv * 32;

    float eqc[2];
#pragma unroll
    for (int nf = 0; nf < 2; ++nf) eqc[nf] = esq[cbase + cg2 * 32 + nf * 16 + rl];

    const f32x4 zero4 = {0.f, 0.f, 0.f, 0.f};
    f32x4 acc[4][2];
#pragma unroll
    for (int a = 0; a < 4; ++a)
#pragma unroll
        for (int b = 0; b < 2; ++b) acc[a][b] = zero4;
    float av[2] = {0.f, 0.f};

    {
#pragma unroll
        for (int i = 0; i < 2; ++i) {
            size_t go = (size_t)(nbase + Rb + i * 16 + srow) * DIMD + sg * 8;
            gl16(zh + go, &sStr[0][0][Rb + i * 16][0]);
            gl16(zl + go, &sStr[0][1][Rb + i * 16][0]);
        }
    }
    __syncthreads();

    for (int c = 0; c < 128; ++c) {
        if (c < 127) {
            int cn = c + 1;
            int b = cn & 1, dc = cn & 7, it = cn >> 3;
            int ntb = nbase + it * 256;
#pragma unroll
            for (int i = 0; i < 2; ++i) {
                size_t go = (size_t)(ntb + Rb + i * 16 + srow) * DIMD + dc * 32 + sg * 8;
                gl16(zh + go, &sStr[b][0][Rb + i * 16][0]);
                gl16(zl + go, &sStr[b][1][Rb + i * 16][0]);
            }
        }
        {
            const int b = c & 1, dc = c & 7;
            const char* sb = (const char*)sStr + b * 32768;
            bf16x8 zfr[4][2];
#pragma unroll
            for (int mf = 0; mf < 4; ++mf) {
                zfr[mf][0] = *(const bf16x8*)(sb + strOff + mf * 1024);
                zfr[mf][1] = *(const bf16x8*)(sb + 16384 + strOff + mf * 1024);
            }
            const char* ebH = (const char*)sOwnH;
            const char* ebL = (const char*)sOwnL;
            bf16x8 efr[2][2];
#pragma unroll
            for (int nf = 0; nf < 2; ++nf) {
                efr[nf][0] = *(const bf16x8*)(ebH + ownOff + nf * 8448 + dc * 64);
                efr[nf][1] = *(const bf16x8*)(ebL + ownOff + nf * 8448 + dc * 64);
            }
#pragma unroll
            for (int mf = 0; mf < 4; ++mf)
#pragma unroll
                for (int nf = 0; nf < 2; ++nf) {
                    acc[mf][nf] = __builtin_amdgcn_mfma_f32_16x16x32_bf16(zfr[mf][0], efr[nf][0], acc[mf][nf], 0, 0, 0);
                    acc[mf][nf] = __builtin_amdgcn_mfma_f32_16x16x32_bf16(zfr[mf][0], efr[nf][1], acc[mf][nf], 0, 0, 0);
                    acc[mf][nf] = __builtin_amdgcn_mfma_f32_16x16x32_bf16(zfr[mf][1], efr[nf][0], acc[mf][nf], 0, 0, 0);
                }
        }
        if ((c & 7) == 7) {
            const int it = c >> 3;
#pragma unroll
            for (int mf = 0; mf < 4; ++mf) {
                f32x4 mv = *(const f32x4*)(mls + nbase + it * 256 + tg4 * 64 + mf * 16 + g * 4);
#pragma unroll
                for (int nf = 0; nf < 2; ++nf) {
                    f32x4 a = acc[mf][nf];
#pragma unroll
                    for (int r = 0; r < 4; ++r) {
                        float x = fmaf(200.f, a[r], -100.f * eqc[nf]) - mv[r];
                        av[nf] += __expf(x);
                    }
                    acc[mf][nf] = zero4;
                }
            }
        }
        __syncthreads();
    }

#pragma unroll
    for (int nf = 0; nf < 2; ++nf) {
        av[nf] += __shfl_xor(av[nf], 16, 64);
        av[nf] += __shfl_xor(av[nf], 32, 64);
    }
    float* sAv = (float*)sStr;
    if (lane < 16) {
        sAv[tg4 * 64 + cg2 * 32 + lane] = av[0];
        sAv[tg4 * 64 + cg2 * 32 + 16 + lane] = av[1];
    }
    __syncthreads();
    if (tid < 64) {
        float ssum = sAv[tid] + sAv[64 + tid] + sAv[128 + tid] + sAv[192 + tid];
        atomicAdd(&avgp[cbase + tid], ssum);
    }
}

// ---------------------------------------------------------------- gather z_q + vq sum
__global__ __launch_bounds__(256) void gather_zq(const float* __restrict__ z,
    const float* __restrict__ zinvp, const float* __restrict__ emb,
    const float* __restrict__ einvp, const int* __restrict__ idx,
    float* __restrict__ out, float* __restrict__ vq)
{
    int bh = blockIdx.x;
    int c  = threadIdx.x;
    const float* zp = z + (size_t)(bh >> 4) * 65536 + (size_t)c * 256 + (size_t)(bh & 15) * 16;
    float buf[16];
    float sum = 0.f;
#pragma unroll
    for (int w = 0; w < 16; ++w) {
        int n = bh * 16 + w;
        int k = idx[n];
        float q  = emb[(size_t)k * DIMD + c] * einvp[k];
        float zv = zp[w] * zinvp[n];
        float d = q - zv;
        sum += d * d;
        buf[w] = q;
    }
    float* dst = out + (size_t)(bh >> 4) * 65536 + (size_t)c * 256 + (size_t)(bh & 15) * 16;
    *(float4*)(dst + 0)  = make_float4(buf[0],  buf[1],  buf[2],  buf[3]);
    *(float4*)(dst + 4)  = make_float4(buf[4],  buf[5],  buf[6],  buf[7]);
    *(float4*)(dst + 8)  = make_float4(buf[8],  buf[9],  buf[10], buf[11]);
    *(float4*)(dst + 12) = make_float4(buf[12], buf[13], buf[14], buf[15]);
#pragma unroll
    for (int o = 32; o > 0; o >>= 1) sum += __shfl_xor(sum, o, 64);
    __shared__ float red[4];
    if ((c & 63) == 0) red[c >> 6] = sum;
    __syncthreads();
    if (c == 0) atomicAdd(vq, red[0] + red[1] + red[2] + red[3]);
}

// ---------------------------------------------------------------- finalize
__global__ __launch_bounds__(256) void finalize(const float* __restrict__ avgp,
    const float* __restrict__ scal, float* __restrict__ out3)
{
    int tid = threadIdx.x;
    float local = 0.f;
    for (int k = tid; k < NCODE; k += 256) {
        float a = avgp[k] * (1.0f / 8192.0f);
        local += a * logf(a + 1e-5f);
    }
    __shared__ float red[256];
    red[tid] = local;
    __syncthreads();
    for (int o = 128; o > 0; o >>= 1) {
        if (tid < o) red[tid] += red[tid + o];
        __syncthreads();
    }
    if (tid == 0) {
        float avg_entropy = -red[0];
        float sample_entropy = -(scal[0] * (1.0f / 8192.0f));
        float ent = 0.1f * (sample_entropy - avg_entropy);
        float vql = scal[1] * (1.0f / 2097152.0f);
        out3[0] = vql;
        out3[1] = 0.25f * vql;
        out3[2] = ent;
    }
}

extern "C" void kernel_launch(void* const* d_in, const int* in_sizes, int n_in,
                              void* d_out, int out_size, void* d_ws, size_t ws_size,
                              hipStream_t stream)
{
    const float* z   = (const float*)d_in[0];
    const float* emb = (const float*)d_in[1];
    float* ws = (float*)d_ws;

    unsigned short* zh = (unsigned short*)ws;               // 2M bf16
    unsigned short* zl = (unsigned short*)(ws + 1048576);
    unsigned short* eh = (unsigned short*)(ws + 2097152);
    unsigned short* el = (unsigned short*)(ws + 3145728);
    float* esq  = ws + 4194304;        // 8192
    float* einv = esq + 8192;
    float* zinv = einv + 8192;
    int*   idx  = (int*)(zinv + 8192);
    float* avgp = (float*)(idx + 8192);
    float* scal = avgp + 8192;         // [0]=sum p*logp, [1]=vq sum

    // small scratch lives in d_out's z_q region (dead before gather overwrites)
    float* outq = (float*)d_out;
    float* out3 = outq + 2097152;
    float* pm1 = outq;                 // 16384
    int*   pi1 = (int*)(outq + 16384);
    int*   pi2 = (int*)(outq + 32768);
    float* psv = outq + 49152;
    float* puv = outq + 65536;
    float* mls = outq + 81920;         // 8192

    prep_z<<<512, 256, 0, stream>>>(z, zh, zl, zinv);
    prep_e<<<2048, 256, 0, stream>>>(emb, eh, el, esq, einv, avgp, scal);
    pass1<<<256, 512, 0, stream>>>(eh, el, zh, zl, esq, pm1, pi1, pi2, psv, puv);
    merge_halves<<<32, 256, 0, stream>>>(pm1, psv, puv, mls, scal);
    fixup<<<1024, 512, 0, stream>>>(z, zinv, emb, einv, esq, pi1, pi2, idx);
    pass2<<<256, 512, 0, stream>>>(eh, el, zh, zl, esq, mls, avgp);
    gather_zq<<<512, 256, 0, stream>>>(z, zinv, emb, einv, idx, outq, scal + 1);
    finalize<<<1, 256, 0, stream>>>(avgp, scal, out3);
}

// Round 5
// 217.753 us; speedup vs baseline: 7.3627x; 1.7263x over previous
//
#include <hip/hip_runtime.h>
#include <math.h>

#define NTOK 8192
#define NCODE 8192
#define DIMD 256

typedef _Float16 f16;
typedef _Float16 f16x8 __attribute__((ext_vector_type(8)));
typedef float f32x4 __attribute__((ext_vector_type(4)));

__device__ __forceinline__ float4 ldg4(const float* p) {
    return *reinterpret_cast<const float4*>(p);
}
__device__ __forceinline__ unsigned short f2h(float x) {
    f16 h = (f16)x;
    return __builtin_bit_cast(unsigned short, h);
}
__device__ __forceinline__ void gl16(const void* g, void* l) {
    __builtin_amdgcn_global_load_lds(
        (const __attribute__((address_space(1))) unsigned int*)g,
        (__attribute__((address_space(3))) unsigned int*)l, 16, 0, 0);
}
__device__ __forceinline__ bool gtvi(float av, int ai, float bv, int bi) {
    return (av > bv) || (av == bv && ai < bi);
}
// merge sorted-desc triple (a) with sorted-desc triple (b) -> top-3 into a
__device__ __forceinline__ void merge3(float& a1, int& a1i, float& a2, int& a2i, float& a3, int& a3i,
                                       float b1, int b1i, float b2, int b2i, float b3, int b3i)
{
    bool w1 = gtvi(b1, b1i, a1, a1i);
    float r1 = w1 ? b1 : a1; int r1i = w1 ? b1i : a1i;
    float aH = w1 ? a1 : a2; int aHi = w1 ? a1i : a2i;
    float aN = w1 ? a2 : a3; int aNi = w1 ? a2i : a3i;
    float bH = w1 ? b2 : b1; int bHi = w1 ? b2i : b1i;
    float bN = w1 ? b3 : b2; int bNi = w1 ? b3i : b2i;
    bool w2 = gtvi(bH, bHi, aH, aHi);
    float r2 = w2 ? bH : aH; int r2i = w2 ? bHi : aHi;
    float aH2 = w2 ? aH : aN; int aH2i = w2 ? aHi : aNi;
    float bH2 = w2 ? bN : bH; int bH2i = w2 ? bNi : bHi;
    bool w3 = gtvi(bH2, bH2i, aH2, aH2i);
    a1 = r1; a1i = r1i; a2 = r2; a2i = r2i;
    a3 = w3 ? bH2 : aH2; a3i = w3 ? bH2i : aH2i;
}

// ---------------------------------------------------------------- prep_z
__global__ __launch_bounds__(256) void prep_z(const float* __restrict__ z,
    f16* __restrict__ zf, float* __restrict__ zinvp)
{
    int bh = blockIdx.x;           // b*16 + h
    int c  = threadIdx.x;          // channel
    const float* src = z + (size_t)(bh >> 4) * 65536 + (size_t)c * 256 + (size_t)(bh & 15) * 16;
    float v[16];
    float4 t0 = ldg4(src + 0), t1 = ldg4(src + 4), t2 = ldg4(src + 8), t3 = ldg4(src + 12);
    v[0]=t0.x; v[1]=t0.y; v[2]=t0.z; v[3]=t0.w;
    v[4]=t1.x; v[5]=t1.y; v[6]=t1.z; v[7]=t1.w;
    v[8]=t2.x; v[9]=t2.y; v[10]=t2.z; v[11]=t2.w;
    v[12]=t3.x; v[13]=t3.y; v[14]=t3.z; v[15]=t3.w;

    float sq[16];
#pragma unroll
    for (int w = 0; w < 16; ++w) sq[w] = v[w] * v[w];
#pragma unroll
    for (int o = 32; o > 0; o >>= 1) {
#pragma unroll
        for (int w = 0; w < 16; ++w) sq[w] += __shfl_xor(sq[w], o, 64);
    }
    __shared__ float part[4][16];
    __shared__ float invS[16];
    int wave = c >> 6, lane = c & 63;
    if (lane == 0) {
#pragma unroll
        for (int w = 0; w < 16; ++w) part[wave][w] = sq[w];
    }
    __syncthreads();
    if (c < 16) {
        float s = part[0][c] + part[1][c] + part[2][c] + part[3][c];
        float iv = 1.0f / sqrtf(s + 1e-12f);
        invS[c] = iv;
        zinvp[bh * 16 + c] = iv;
    }
    __syncthreads();
#pragma unroll
    for (int w = 0; w < 16; ++w) {
        zf[(size_t)(bh * 16 + w) * DIMD + c] = (f16)(v[w] * invS[w]);
    }
}

// ---------------------------------------------------------------- prep_e
__global__ __launch_bounds__(256) void prep_e(const float* __restrict__ e,
    f16* __restrict__ ef, float* __restrict__ esq, float* __restrict__ einvp,
    float* __restrict__ scal)
{
    if (blockIdx.x == 0 && threadIdx.x < 2) scal[threadIdx.x] = 0.0f;
    int row  = blockIdx.x * 4 + (threadIdx.x >> 6);
    int lane = threadIdx.x & 63;
    float4 v = ldg4(e + (size_t)row * DIMD + lane * 4);
    float ss = v.x*v.x + v.y*v.y + v.z*v.z + v.w*v.w;
#pragma unroll
    for (int o = 32; o > 0; o >>= 1) ss += __shfl_xor(ss, o, 64);
    float inv = 1.0f / sqrtf(ss + 1e-12f);
    float w4[4] = { v.x*inv, v.y*inv, v.z*inv, v.w*inv };
    ushort4 pk;
    pk.x = f2h(w4[0]); pk.y = f2h(w4[1]); pk.z = f2h(w4[2]); pk.w = f2h(w4[3]);
    *reinterpret_cast<ushort4*>(ef + (size_t)row * DIMD + lane * 4) = pk;
    float s2 = w4[0]*w4[0] + w4[1]*w4[1] + w4[2]*w4[2] + w4[3]*w4[3];
#pragma unroll
    for (int o = 32; o > 0; o >>= 1) s2 += __shfl_xor(s2, o, 64);
    if (lane == 0) { esq[row] = s2; einvp[row] = inv; }
}

// ---------------------------------------------------------------- pass1
// D[code][token] f16 MFMA GEMM, logits l = 200*dot - 100*esq[k] (row const
// 100*zsq dropped). Online softmax (m,s,u) + TOP-3 per token per half.
__global__ __launch_bounds__(512, 2) void pass1(
    const f16* __restrict__ ef, const f16* __restrict__ zf,
    const float* __restrict__ esq,
    float* __restrict__ pm1, int* __restrict__ pi1, int* __restrict__ pi2,
    int* __restrict__ pi3, float* __restrict__ psv, float* __restrict__ puv)
{
    __shared__ __align__(16) char sBuf[2][32768];

    const int tid = threadIdx.x;
    const int lane = tid & 63;
    const int wv = tid >> 6;
    const int tkbase = (int)(blockIdx.x >> 1) * 64;
    const int half = blockIdx.x & 1;
    const int kbase = half * 4096;

    f16x8 zfr[4][8];   // 64 tokens x 256 dims, in regs (128 VGPR)

    // ---- prologue: stage tokens (swizzled) into sBuf[0], read frags to regs
    {
#pragma unroll
        for (int i = 0; i < 4; ++i) {
            int row = wv * 8 + i * 2 + (lane >> 5);
            int chunk = (lane & 31) ^ ((i * 2 + (lane >> 5)) & 7);
            gl16(zf + (size_t)(tkbase + row) * DIMD + chunk * 8,
                 sBuf[0] + wv * 4096 + i * 1024 + lane * 16);
        }
        __syncthreads();
#pragma unroll
        for (int tf = 0; tf < 4; ++tf) {
            int row = tf * 16 + (lane & 15);
#pragma unroll
            for (int ks = 0; ks < 8; ++ks) {
                int slot = (ks * 4 + (lane >> 4)) ^ (lane & 7);
                zfr[tf][ks] = *(const f16x8*)(sBuf[0] + row * 512 + slot * 16);
            }
        }
        __syncthreads();
    }

    auto STAGE = [&](int c) {
        int tile = c >> 2, dc = c & 3;
        const f16* src = ef + (size_t)(kbase + tile * 256) * DIMD + dc * 64;
        char* dst = sBuf[c & 1] + wv * 4096 + lane * 16;
        int rbase = wv * 32 + (lane >> 3);
        int chunk = (lane & 7) ^ ((lane >> 3) & 7);
#pragma unroll
        for (int i = 0; i < 4; ++i)
            gl16(src + (size_t)(rbase + i * 8) * DIMD + chunk * 8, dst + i * 1024);
    };

    const f32x4 zero4 = {0.f, 0.f, 0.f, 0.f};
    f32x4 acc[2][4];
#pragma unroll
    for (int a = 0; a < 2; ++a)
#pragma unroll
        for (int b = 0; b < 4; ++b) acc[a][b] = zero4;

    float m1[4], m2[4], m3[4], sS[4], uU[4];
    int i1[4], i2[4], i3[4];
#pragma unroll
    for (int t = 0; t < 4; ++t) {
        m1[t] = -3.0e38f; m2[t] = -3.0e38f; m3[t] = -3.0e38f;
        sS[t] = 0.f; uU[t] = 0.f; i1[t] = 0; i2[t] = 0; i3[t] = 0;
    }

    STAGE(0);
    __syncthreads();

    for (int tile = 0; tile < 16; ++tile) {
#pragma unroll
        for (int dc = 0; dc < 4; ++dc) {
            int c = tile * 4 + dc;
            if (c < 63) STAGE(c + 1);
            const char* sb = sBuf[c & 1];
#pragma unroll
            for (int k32 = 0; k32 < 2; ++k32) {
                f16x8 efr[2];
#pragma unroll
                for (int cf = 0; cf < 2; ++cf) {
                    int row = wv * 32 + cf * 16 + (lane & 15);
                    int slot = (k32 * 4 + (lane >> 4)) ^ (lane & 7);
                    efr[cf] = *(const f16x8*)(sb + row * 128 + slot * 16);
                }
                const int ks = dc * 2 + k32;
#pragma unroll
                for (int cf = 0; cf < 2; ++cf)
#pragma unroll
                    for (int tf = 0; tf < 4; ++tf)
                        acc[cf][tf] = __builtin_amdgcn_mfma_f32_16x16x32_f16(efr[cf], zfr[tf][ks], acc[cf][tf], 0, 0, 0);
            }
            if (dc == 3) {
                // epilogue for this 256-code tile
                const int codeB = kbase + tile * 256 + wv * 32 + (lane >> 4) * 4;
                f32x4 qv[2];
                qv[0] = *(const f32x4*)(esq + codeB);
                qv[1] = *(const f32x4*)(esq + codeB + 16);
#pragma unroll
                for (int tf = 0; tf < 4; ++tf) {
                    float xs[2][4];
                    float t1 = -3.0e38f, t2 = -3.0e38f, t3 = -3.0e38f;
                    int ti1 = 0, ti2 = 0, ti3 = 0;
#pragma unroll
                    for (int cf = 0; cf < 2; ++cf)
#pragma unroll
                        for (int r = 0; r < 4; ++r) {
                            float x = fmaf(200.f, acc[cf][tf][r], -100.f * qv[cf][r]);
                            xs[cf][r] = x;
                            int cid = codeB + cf * 16 + r;
                            // ascending cid insert (strict > keeps earlier on tie)
                            bool c1 = x > t1, c2 = x > t2, c3 = x > t3;
                            t3 = c2 ? t2 : (c3 ? x : t3); ti3 = c2 ? ti2 : (c3 ? cid : ti3);
                            t2 = c1 ? t1 : (c2 ? x : t2); ti2 = c1 ? ti1 : (c2 ? cid : ti2);
                            t1 = c1 ? x  : t1;            ti1 = c1 ? cid : ti1;
                        }
#pragma unroll
                    for (int off = 16; off <= 32; off <<= 1) {
                        float o1 = __shfl_xor(t1, off, 64); int oi1 = __shfl_xor(ti1, off, 64);
                        float o2 = __shfl_xor(t2, off, 64); int oi2 = __shfl_xor(ti2, off, 64);
                        float o3 = __shfl_xor(t3, off, 64); int oi3 = __shfl_xor(ti3, off, 64);
                        merge3(t1, ti1, t2, ti2, t3, ti3, o1, oi1, o2, oi2, o3, oi3);
                    }
                    float mOld = m1[tf];
                    merge3(m1[tf], i1[tf], m2[tf], i2[tf], m3[tf], i3[tf],
                           t1, ti1, t2, ti2, t3, ti3);
                    float mn = m1[tf];
                    float ps = 0.f, pu = 0.f;
#pragma unroll
                    for (int cf = 0; cf < 2; ++cf)
#pragma unroll
                        for (int r = 0; r < 4; ++r) {
                            float xm = xs[cf][r] - mn;
                            float e2 = __expf(xm);
                            ps += e2;
                            pu = fmaf(e2, xm, pu);
                        }
                    float dm = mOld - mn;          // finite sentinel
                    float al = __expf(dm);
                    uU[tf] = al * (uU[tf] + sS[tf] * dm) + pu;
                    sS[tf] = al * sS[tf] + ps;
#pragma unroll
                    for (int cf = 0; cf < 2; ++cf) acc[cf][tf] = zero4;
                }
            }
            __syncthreads();
        }
    }

    // reduce per-lane s/u partials across the 4 lane-groups of each token
#pragma unroll
    for (int tf = 0; tf < 4; ++tf) {
        sS[tf] += __shfl_xor(sS[tf], 16, 64); sS[tf] += __shfl_xor(sS[tf], 32, 64);
        uU[tf] += __shfl_xor(uU[tf], 16, 64); uU[tf] += __shfl_xor(uU[tf], 32, 64);
    }

    // cross-wave (code-slice) merge; 8 floats per (wave, token)
    float* sRed = (float*)sBuf;
    if ((lane >> 4) == 0) {
#pragma unroll
        for (int tf = 0; tf < 4; ++tf) {
            int t = tf * 16 + (lane & 15);
            float* p = sRed + (wv * 64 + t) * 8;
            p[0] = m1[tf]; p[1] = __int_as_float(i1[tf]);
            p[2] = m2[tf]; p[3] = __int_as_float(i2[tf]);
            p[4] = m3[tf]; p[5] = __int_as_float(i3[tf]);
            p[6] = sS[tf]; p[7] = uU[tf];
        }
    }
    __syncthreads();
    if (tid < 64) {
        const float* p0 = sRed + tid * 8;
        float am1 = p0[0], am2 = p0[2], am3 = p0[4], as_ = p0[6], au = p0[7];
        int ai1 = __float_as_int(p0[1]), ai2 = __float_as_int(p0[3]), ai3 = __float_as_int(p0[5]);
#pragma unroll
        for (int w = 1; w < 8; ++w) {
            const float* pb = sRed + (w * 64 + tid) * 8;
            float bm1 = pb[0], bm2 = pb[2], bm3 = pb[4], bs = pb[6], bu = pb[7];
            int bi1 = __float_as_int(pb[1]), bi2 = __float_as_int(pb[3]), bi3 = __float_as_int(pb[5]);
            float M = fmaxf(am1, bm1);
            float da = am1 - M, db = bm1 - M;
            float ea = __expf(da), eb = __expf(db);
            float ns = ea * as_ + eb * bs;
            float nu = ea * (au + as_ * da) + eb * (bu + bs * db);
            merge3(am1, ai1, am2, ai2, am3, ai3, bm1, bi1, bm2, bi2, bm3, bi3);
            as_ = ns; au = nu;
        }
        int o = half * NTOK + tkbase + tid;
        pm1[o] = am1; pi1[o] = ai1; pi2[o] = ai2; pi3[o] = ai3; psv[o] = as_; puv[o] = au;
    }
}

// ---------------------------------------------------------------- merge_halves
__global__ __launch_bounds__(256) void merge_halves(
    const float* __restrict__ pm1, const float* __restrict__ psv, const float* __restrict__ puv,
    float* __restrict__ mls, float* __restrict__ samp)
{
    int n = blockIdx.x * 256 + threadIdx.x;
    float m0 = pm1[n], m1_ = pm1[NTOK + n];
    float s0 = psv[n], s1 = psv[NTOK + n];
    float u0 = puv[n], u1 = puv[NTOK + n];
    float M = fmaxf(m0, m1_);
    float d0 = m0 - M, d1 = m1_ - M;
    float e0 = __expf(d0), e1 = __expf(d1);
    float ss = e0 * s0 + e1 * s1;
    float uu = e0 * (u0 + s0 * d0) + e1 * (u1 + s1 * d1);
    float lnS = logf(ss);
    mls[n] = M + lnS;
    float plogp = uu / ss - lnS;
    __shared__ float red[256];
    red[threadIdx.x] = plogp;
    __syncthreads();
    for (int o = 128; o > 0; o >>= 1) {
        if (threadIdx.x < o) red[threadIdx.x] += red[threadIdx.x + o];
        __syncthreads();
    }
    if (threadIdx.x == 0) atomicAdd(samp, red[0]);
}

// ---------------------------------------------------------------- fixup
// exact f32 argmin over the 6 top-3 candidates (3 per half), ref tie rules
__global__ __launch_bounds__(512) void fixup(const float* __restrict__ z, const float* __restrict__ zinvp,
    const float* __restrict__ emb, const float* __restrict__ einvp, const float* __restrict__ esq,
    const int* __restrict__ pi1, const int* __restrict__ pi2, const int* __restrict__ pi3,
    int* __restrict__ idx)
{
    int wv = threadIdx.x >> 6, lane = threadIdx.x & 63;
    int n = blockIdx.x * 8 + wv;
    int cand[6] = { pi1[n], pi2[n], pi3[n], pi1[NTOK + n], pi2[NTOK + n], pi3[NTOK + n] };
    int b = n >> 8, hw = n & 255;
    float zi = zinvp[n];
    float dd[6] = {0.f, 0.f, 0.f, 0.f, 0.f, 0.f};
    const float* zp = z + (size_t)b * 65536 + hw;
    for (int d = lane; d < 256; d += 64) {
        float zv = zp[(size_t)d * 256] * zi;
#pragma unroll
        for (int k = 0; k < 6; ++k) dd[k] = fmaf(zv, emb[(size_t)cand[k] * 256 + d], dd[k]);
    }
#pragma unroll
    for (int off = 1; off < 64; off <<= 1) {
#pragma unroll
        for (int k = 0; k < 6; ++k) dd[k] += __shfl_xor(dd[k], off, 64);
    }
    if (lane == 0) {
        float bD = 3.0e38f; int bi = 0x7fffffff;
#pragma unroll
        for (int k = 0; k < 6; ++k) {
            float D = esq[cand[k]] - 2.f * dd[k] * einvp[cand[k]];
            bool win = (D < bD) || (D == bD && cand[k] < bi);
            bD = win ? D : bD; bi = win ? cand[k] : bi;
        }
        idx[n] = bi;
    }
}

// ---------------------------------------------------------------- pass2
// avg_probs: WG owns 64 codes in REGISTERS, streams 4096 tokens (one half).
__global__ __launch_bounds__(512, 2) void pass2(
    const f16* __restrict__ ef, const f16* __restrict__ zf,
    const float* __restrict__ esq, const float* __restrict__ mls,
    float* __restrict__ avgp)
{
    __shared__ __align__(16) char sBuf[2][32768];

    const int tid = threadIdx.x;
    const int lane = tid & 63;
    const int wv = tid >> 6;
    const int cbase = (int)(blockIdx.x >> 1) * 64;
    const int half = blockIdx.x & 1;
    const int nbase = half * 4096;

    f16x8 cfr[4][8];   // 64 codes x 256 dims, in regs

    {
#pragma unroll
        for (int i = 0; i < 4; ++i) {
            int row = wv * 8 + i * 2 + (lane >> 5);
            int chunk = (lane & 31) ^ ((i * 2 + (lane >> 5)) & 7);
            gl16(ef + (size_t)(cbase + row) * DIMD + chunk * 8,
                 sBuf[0] + wv * 4096 + i * 1024 + lane * 16);
        }
        __syncthreads();
#pragma unroll
        for (int cf = 0; cf < 4; ++cf) {
            int row = cf * 16 + (lane & 15);
#pragma unroll
            for (int ks = 0; ks < 8; ++ks) {
                int slot = (ks * 4 + (lane >> 4)) ^ (lane & 7);
                cfr[cf][ks] = *(const f16x8*)(sBuf[0] + row * 512 + slot * 16);
            }
        }
        __syncthreads();
    }

    // per-lane esq for acc rows: code = cbase + cf*16 + (lane>>4)*4 + r
    f32x4 eqv[4];
#pragma unroll
    for (int cf = 0; cf < 4; ++cf)
        eqv[cf] = *(const f32x4*)(esq + cbase + cf * 16 + (lane >> 4) * 4);

    auto STAGE = [&](int c) {
        int tile = c >> 2, dc = c & 3;
        const f16* src = zf + (size_t)(nbase + tile * 256) * DIMD + dc * 64;
        char* dst = sBuf[c & 1] + wv * 4096 + lane * 16;
        int rbase = wv * 32 + (lane >> 3);
        int chunk = (lane & 7) ^ ((lane >> 3) & 7);
#pragma unroll
        for (int i = 0; i < 4; ++i)
            gl16(src + (size_t)(rbase + i * 8) * DIMD + chunk * 8, dst + i * 1024);
    };

    const f32x4 zero4 = {0.f, 0.f, 0.f, 0.f};
    f32x4 acc[4][2];
#pragma unroll
    for (int a = 0; a < 4; ++a)
#pragma unroll
        for (int b = 0; b < 2; ++b) acc[a][b] = zero4;
    float av[4][4];
#pragma unroll
    for (int a = 0; a < 4; ++a)
#pragma unroll
        for (int r = 0; r < 4; ++r) av[a][r] = 0.f;
    float mlsv[2] = {0.f, 0.f};

    STAGE(0);
    __syncthreads();

    for (int tile = 0; tile < 16; ++tile) {
#pragma unroll
        for (int dc = 0; dc < 4; ++dc) {
            int c = tile * 4 + dc;
            if (c < 63) STAGE(c + 1);
            if (dc == 0) {
#pragma unroll
                for (int tf = 0; tf < 2; ++tf)
                    mlsv[tf] = mls[nbase + tile * 256 + wv * 32 + tf * 16 + (lane & 15)];
            }
            const char* sb = sBuf[c & 1];
#pragma unroll
            for (int k32 = 0; k32 < 2; ++k32) {
                f16x8 ztf[2];
#pragma unroll
                for (int tf = 0; tf < 2; ++tf) {
                    int row = wv * 32 + tf * 16 + (lane & 15);
                    int slot = (k32 * 4 + (lane >> 4)) ^ (lane & 7);
                    ztf[tf] = *(const f16x8*)(sb + row * 128 + slot * 16);
                }
                const int ks = dc * 2 + k32;
#pragma unroll
                for (int cf = 0; cf < 4; ++cf)
#pragma unroll
                    for (int tf = 0; tf < 2; ++tf)
                        acc[cf][tf] = __builtin_amdgcn_mfma_f32_16x16x32_f16(cfr[cf][ks], ztf[tf], acc[cf][tf], 0, 0, 0);
            }
            if (dc == 3) {
#pragma unroll
                for (int cf = 0; cf < 4; ++cf)
#pragma unroll
                    for (int tf = 0; tf < 2; ++tf) {
#pragma unroll
                        for (int r = 0; r < 4; ++r) {
                            float x = fmaf(200.f, acc[cf][tf][r],
                                           fmaf(-100.f, eqv[cf][r], -mlsv[tf]));
                            av[cf][r] += __expf(x);
                        }
                        acc[cf][tf] = zero4;
                    }
            }
            __syncthreads();
        }
    }

    // reduce av over the 16 token-columns within each lane group
#pragma unroll
    for (int cf = 0; cf < 4; ++cf)
#pragma unroll
        for (int r = 0; r < 4; ++r) {
#pragma unroll
            for (int off = 1; off <= 8; off <<= 1)
                av[cf][r] += __shfl_xor(av[cf][r], off, 64);
        }
    float* sAv = (float*)sBuf;
    if ((lane & 15) == 0) {
#pragma unroll
        for (int cf = 0; cf < 4; ++cf)
#pragma unroll
            for (int r = 0; r < 4; ++r)
                sAv[wv * 64 + cf * 16 + (lane >> 4) * 4 + r] = av[cf][r];
    }
    __syncthreads();
    if (tid < 64) {
        float s = 0.f;
#pragma unroll
        for (int w = 0; w < 8; ++w) s += sAv[w * 64 + tid];
        avgp[half * NCODE + cbase + tid] = s;
    }
}

// ---------------------------------------------------------------- gather z_q + vq sum
__global__ __launch_bounds__(256) void gather_zq(const float* __restrict__ z,
    const float* __restrict__ zinvp, const float* __restrict__ emb,
    const float* __restrict__ einvp, const int* __restrict__ idx,
    float* __restrict__ out, float* __restrict__ vq)
{
    int bh = blockIdx.x;
    int c  = threadIdx.x;
    const float* zp = z + (size_t)(bh >> 4) * 65536 + (size_t)c * 256 + (size_t)(bh & 15) * 16;
    float buf[16];
    float sum = 0.f;
#pragma unroll
    for (int w = 0; w < 16; ++w) {
        int n = bh * 16 + w;
        int k = idx[n];
        float q  = emb[(size_t)k * DIMD + c] * einvp[k];
        float zv = zp[w] * zinvp[n];
        float d = q - zv;
        sum += d * d;
        buf[w] = q;
    }
    float* dst = out + (size_t)(bh >> 4) * 65536 + (size_t)c * 256 + (size_t)(bh & 15) * 16;
    *(float4*)(dst + 0)  = make_float4(buf[0],  buf[1],  buf[2],  buf[3]);
    *(float4*)(dst + 4)  = make_float4(buf[4],  buf[5],  buf[6],  buf[7]);
    *(float4*)(dst + 8)  = make_float4(buf[8],  buf[9],  buf[10], buf[11]);
    *(float4*)(dst + 12) = make_float4(buf[12], buf[13], buf[14], buf[15]);
#pragma unroll
    for (int o = 32; o > 0; o >>= 1) sum += __shfl_xor(sum, o, 64);
    __shared__ float red[4];
    if ((c & 63) == 0) red[c >> 6] = sum;
    __syncthreads();
    if (c == 0) atomicAdd(vq, red[0] + red[1] + red[2] + red[3]);
}

// ---------------------------------------------------------------- finalize
__global__ __launch_bounds__(256) void finalize(const float* __restrict__ avgp,
    const float* __restrict__ scal, float* __restrict__ out3)
{
    int tid = threadIdx.x;
    float local = 0.f;
    for (int k = tid; k < NCODE; k += 256) {
        float a = (avgp[k] + avgp[NCODE + k]) * (1.0f / 8192.0f);
        local += a * logf(a + 1e-5f);
    }
    __shared__ float red[256];
    red[tid] = local;
    __syncthreads();
    for (int o = 128; o > 0; o >>= 1) {
        if (tid < o) red[tid] += red[tid + o];
        __syncthreads();
    }
    if (tid == 0) {
        float avg_entropy = -red[0];
        float sample_entropy = -(scal[0] * (1.0f / 8192.0f));
        float ent = 0.1f * (sample_entropy - avg_entropy);
        float vql = scal[1] * (1.0f / 2097152.0f);
        out3[0] = vql;
        out3[1] = 0.25f * vql;
        out3[2] = ent;
    }
}

extern "C" void kernel_launch(void* const* d_in, const int* in_sizes, int n_in,
                              void* d_out, int out_size, void* d_ws, size_t ws_size,
                              hipStream_t stream)
{
    const float* z   = (const float*)d_in[0];
    const float* emb = (const float*)d_in[1];
    float* ws = (float*)d_ws;

    f16* zf16 = (f16*)ws;                      // 8192*256 f16 (4MB)
    f16* ef16 = (f16*)(ws + 1048576);          // 4MB
    float* esq  = ws + 2097152;                // 8192
    float* einv = esq + 8192;
    float* zinv = einv + 8192;
    int*   idx  = (int*)(zinv + 8192);
    float* avgp = (float*)(idx + 8192);        // [2][8192] slices
    float* scal = avgp + 16384;                // [0]=sum p*logp, [1]=vq sum

    // small scratch lives in d_out's z_q region (dead before gather overwrites)
    float* outq = (float*)d_out;
    float* out3 = outq + 2097152;
    float* pm1 = outq;                         // [2][8192]
    int*   pi1 = (int*)(outq + 16384);
    int*   pi2 = (int*)(outq + 32768);
    int*   pi3 = (int*)(outq + 49152);
    float* psv = outq + 65536;
    float* puv = outq + 81920;
    float* mls = outq + 98304;                 // 8192

    prep_z<<<512, 256, 0, stream>>>(z, zf16, zinv);
    prep_e<<<2048, 256, 0, stream>>>(emb, ef16, esq, einv, scal);
    pass1<<<256, 512, 0, stream>>>(ef16, zf16, esq, pm1, pi1, pi2, pi3, psv, puv);
    merge_halves<<<32, 256, 0, stream>>>(pm1, psv, puv, mls, scal);
    fixup<<<1024, 512, 0, stream>>>(z, zinv, emb, einv, esq, pi1, pi2, pi3, idx);
    pass2<<<256, 512, 0, stream>>>(ef16, zf16, esq, mls, avgp);
    gather_zq<<<512, 256, 0, stream>>>(z, zinv, emb, einv, idx, outq, scal + 1);
    finalize<<<1, 256, 0, stream>>>(avgp, scal, out3);
}